// Round 1
// baseline (80.662 us; speedup 1.0000x reference)
//
#include <hip/hip_runtime.h>
#include <cstdint>

// QuLinear: 20-qubit circuit -> marginal probs of 10 MSB qubits (1024 floats).
//
// Algorithm (see theory): post-CNOT state amplitudes are computed analytically
// as amp[y] = prod_q v_q[parity(mask_q & y)] (CNOT block = GF(2)-linear basis
// permutation, composed on host into 20 bit-masks). Final-layer gates on the
// traced-out qubits 10..19 drop under partial trace; only the 10 gates on the
// measured MSB qubits are applied, as in-LDS butterfly stages over the high
// 10 index bits. |amp|^2 is reduced over the low 10 bits.

#define NQ     20
#define NPART  10
#define NH     1024          // 2^NPART, high-bit (measured) dimension
#define NL     1024          // low-bit (traced) dimension
#define BLOCK  256
#define NBLOCKS 256
#define LPB    (NL / NBLOCKS) // l-values per block = 4

struct MaskArg { uint32_t m[NQ]; };

__device__ __forceinline__ float2 cmul(float2 a, float2 b) {
    return make_float2(fmaf(a.x, b.x, -a.y * b.y), fmaf(a.x, b.y, a.y * b.x));
}
__device__ __forceinline__ float2 cadd(float2 a, float2 b) {
    return make_float2(a.x + b.x, a.y + b.y);
}

__global__ __launch_bounds__(BLOCK) void qulinear_kernel(
        const float* __restrict__ x, const float* __restrict__ w,
        float* __restrict__ out, MaskArg masks) {
    __shared__ float2 v[NQ][2];          // per-qubit encoding 2-vectors
    __shared__ float2 U[NPART][2][2];    // Rx*Rz*Rx for measured qubits
    __shared__ float2 psi[NH];           // working 1024-dim vector
    __shared__ float  hid[NH];           // per-block output accumulator

    const int tid = threadIdx.x;

    // --- per-block setup (redundant across blocks; ~trivial cost) ---
    if (tid < NQ) {
        float xq = x[tid];
        float th = atanf(xq);            // ry angle
        float ph = atanf(xq * xq);       // rz angle
        float c, s, cp, sp;
        __sincosf(0.5f * th, &s, &c);
        __sincosf(0.5f * ph, &sp, &cp);
        float a = (c - s) * 0.70710678118654752f;  // Ry*H|0> comp 0
        float b = (c + s) * 0.70710678118654752f;  // comp 1
        v[tid][0] = make_float2(a * cp, -a * sp);  // * e^{-i ph/2}
        v[tid][1] = make_float2(b * cp,  b * sp);  // * e^{+i ph/2}
    }
    if (tid < NPART) {
        const float WM = 0.63245553203367590f;     // sqrt(2/5)
        float a0 = w[3 * tid + 0] * WM;
        float a1 = w[3 * tid + 1] * WM;
        float a2 = w[3 * tid + 2] * WM;
        float c0, s0, c1, s1, c2, s2;
        __sincosf(0.5f * a0, &s0, &c0);
        __sincosf(0.5f * a1, &s1, &c1);
        __sincosf(0.5f * a2, &s2, &c2);
        // M = Rz(a1) * Rx(a0)
        float2 e0 = make_float2(c1, -s1), e1 = make_float2(c1, s1);
        float2 m00 = cmul(e0, make_float2(c0, 0.f));
        float2 m01 = cmul(e0, make_float2(0.f, -s0));
        float2 m10 = cmul(e1, make_float2(0.f, -s0));
        float2 m11 = cmul(e1, make_float2(c0, 0.f));
        // U = Rx(a2) * M
        float2 r00 = make_float2(c2, 0.f), r01 = make_float2(0.f, -s2);
        U[tid][0][0] = cadd(cmul(r00, m00), cmul(r01, m10));
        U[tid][0][1] = cadd(cmul(r00, m01), cmul(r01, m11));
        U[tid][1][0] = cadd(cmul(r01, m00), cmul(r00, m10));
        U[tid][1][1] = cadd(cmul(r01, m01), cmul(r00, m11));
    }
    #pragma unroll
    for (int k = 0; k < NH / BLOCK; ++k) hid[tid + k * BLOCK] = 0.f;
    __syncthreads();

    for (int il = 0; il < LPB; ++il) {
        const uint32_t l = (uint32_t)(blockIdx.x * LPB + il);

        // --- synthesize psi_l[h] analytically ---
        #pragma unroll
        for (int k = 0; k < NH / BLOCK; ++k) {
            int h = tid + k * BLOCK;
            uint32_t y = ((uint32_t)h << NPART) | l;
            float2 amp = make_float2(1.f, 0.f);
            #pragma unroll
            for (int q = 0; q < NQ; ++q) {
                int bit = __popc(masks.m[q] & y) & 1;
                amp = cmul(amp, v[q][bit]);
            }
            psi[h] = amp;
        }
        __syncthreads();

        // --- 10 butterfly stages: apply U_q on h-bit (9-q) ---
        #pragma unroll
        for (int q = 0; q < NPART; ++q) {
            const int p = (NPART - 1) - q;
            #pragma unroll
            for (int j = tid; j < NH / 2; j += BLOCK) {
                int lo = j & ((1 << p) - 1);
                int h0 = ((j >> p) << (p + 1)) | lo;
                int h1 = h0 | (1 << p);
                float2 a = psi[h0], b = psi[h1];
                float2 na = cadd(cmul(U[q][0][0], a), cmul(U[q][0][1], b));
                float2 nb = cadd(cmul(U[q][1][0], a), cmul(U[q][1][1], b));
                psi[h0] = na;
                psi[h1] = nb;
            }
            __syncthreads();
        }

        // --- accumulate |psi|^2 (each h owned by one thread: no races) ---
        #pragma unroll
        for (int k = 0; k < NH / BLOCK; ++k) {
            int h = tid + k * BLOCK;
            float2 a = psi[h];
            hid[h] += fmaf(a.x, a.x, a.y * a.y);
        }
        __syncthreads();
    }

    #pragma unroll
    for (int k = 0; k < NH / BLOCK; ++k) {
        int i = tid + k * BLOCK;
        atomicAdd(&out[i], hid[i]);
    }
}

extern "C" void kernel_launch(void* const* d_in, const int* in_sizes, int n_in,
                              void* d_out, int out_size, void* d_ws, size_t ws_size,
                              hipStream_t stream) {
    const float* x = (const float*)d_in[0];   // (1, 20) f32
    const float* w = (const float*)d_in[1];   // (60,)   f32
    float* out = (float*)d_out;               // (1, 1024) f32

    // Compose the CNOT block into 20 GF(2) row-masks over the index bits.
    // state_after[y] = state_enc[B y]; B = A_1 ... A_40 (A_k applied to y in
    // reverse gate order). Reverse-processing rule: M[target] ^= M[control].
    MaskArg ma;
    {
        uint32_t M[NQ];
        for (int q = 0; q < NQ; ++q) M[q] = 1u << q;       // qubit-index space
        for (int q = NQ - 1; q >= 0; --q) {                 // reverse gate order
            M[(q + 2) % NQ] ^= M[q];                        // CNOT(q, q+2) was later
            M[(q + 1) % NQ] ^= M[q];                        // CNOT(q, q+1) was earlier
        }
        // qubit j lives at index bit (19 - j)
        for (int q = 0; q < NQ; ++q) {
            uint32_t im = 0;
            for (int j = 0; j < NQ; ++j)
                if ((M[q] >> j) & 1) im |= 1u << (NQ - 1 - j);
            ma.m[q] = im;
        }
    }

    hipMemsetAsync(d_out, 0, (size_t)out_size * sizeof(float), stream);
    qulinear_kernel<<<NBLOCKS, BLOCK, 0, stream>>>(x, w, out, ma);
}

// Round 2
// 74.041 us; speedup vs baseline: 1.0894x; 1.0894x over previous
//
#include <hip/hip_runtime.h>
#include <cstdint>

// QuLinear: 20-qubit circuit -> marginal probs of 10 MSB qubits (1024 floats).
//
// Round-2 design: wave-per-l, fully register-resident state.
//   psi(h,l) = prod_q v_q[parity(mask_q & y)],  y = (h<<10)|l   (CNOT block
//   composed on host into GF(2) row-masks). Final-layer gates on traced-out
//   qubits drop under partial trace; the 10 measured-qubit gates U_q are
//   butterfly stages over h. Mapping: h = (r<<6)|lane, r=0..15 per-lane
//   register index. Stages on h-bits 0..5 use __shfl_xor (lane bits);
//   h-bits 6..9 are in-register. No __syncthreads in the main path.

#define NQ      20
#define NPART   10
#define NH      1024
#define BLOCK   256
#define NBLOCKS 256        // 4 waves/block * 256 = 1024 waves = one per l

struct MaskArg { uint32_t m[NQ]; };

__device__ __forceinline__ float2 cmul(float2 a, float2 b) {
    return make_float2(fmaf(a.x, b.x, -a.y * b.y), fmaf(a.x, b.y, a.y * b.x));
}
__device__ __forceinline__ float2 cadd(float2 a, float2 b) {
    return make_float2(a.x + b.x, a.y + b.y);
}

__global__ __launch_bounds__(BLOCK) void qulinear_kernel(
        const float* __restrict__ x, const float* __restrict__ w,
        float* __restrict__ out, MaskArg masks) {
    __shared__ float2   v[NQ][2];        // per-qubit encoding 2-vectors
    __shared__ float2   U[NPART][2][2];  // Rx*Rz*Rx for measured qubits
    __shared__ uint32_t stab[16];        // packed parity deltas for r<<16
    __shared__ float    hid[4][NH];      // per-wave |amp|^2 slabs (16 KB)

    const int tid = threadIdx.x;

    // ---- block setup (v, U, stab) ----
    if (tid < NQ) {
        float xq = x[tid];
        float th = atanf(xq);
        float ph = atanf(xq * xq);
        float c, s, cp, sp;
        __sincosf(0.5f * th, &s, &c);
        __sincosf(0.5f * ph, &sp, &cp);
        float a = (c - s) * 0.70710678118654752f;
        float b = (c + s) * 0.70710678118654752f;
        v[tid][0] = make_float2(a * cp, -a * sp);
        v[tid][1] = make_float2(b * cp,  b * sp);
    }
    if (tid < NPART) {
        const float WM = 0.63245553203367590f;   // sqrt(2/5)
        float a0 = w[3 * tid + 0] * WM;
        float a1 = w[3 * tid + 1] * WM;
        float a2 = w[3 * tid + 2] * WM;
        float c0, s0, c1, s1, c2, s2;
        __sincosf(0.5f * a0, &s0, &c0);
        __sincosf(0.5f * a1, &s1, &c1);
        __sincosf(0.5f * a2, &s2, &c2);
        float2 e0 = make_float2(c1, -s1), e1 = make_float2(c1, s1);
        float2 m00 = cmul(e0, make_float2(c0, 0.f));
        float2 m01 = cmul(e0, make_float2(0.f, -s0));
        float2 m10 = cmul(e1, make_float2(0.f, -s0));
        float2 m11 = cmul(e1, make_float2(c0, 0.f));
        float2 r00 = make_float2(c2, 0.f), r01 = make_float2(0.f, -s2);
        U[tid][0][0] = cadd(cmul(r00, m00), cmul(r01, m10));
        U[tid][0][1] = cadd(cmul(r00, m01), cmul(r01, m11));
        U[tid][1][0] = cadd(cmul(r01, m00), cmul(r00, m10));
        U[tid][1][1] = cadd(cmul(r01, m01), cmul(r00, m11));
    }
    if (tid < 16) {
        uint32_t y = (uint32_t)tid << 16;   // h-bits 6..9 live at y-bits 16..19
        uint32_t s = 0;
        #pragma unroll
        for (int q = 0; q < NQ; ++q)
            s |= (uint32_t)(__popc(masks.m[q] & y) & 1) << q;
        stab[tid] = s;
    }
    __syncthreads();

    const int wave = tid >> 6;
    const int lane = tid & 63;
    const uint32_t l = (uint32_t)(blockIdx.x * 4 + wave);

    // ---- per-lane packed parity words: s[r] has bit q = parity(m_q & y_r) ----
    const uint32_t y0 = ((uint32_t)lane << NPART) | l;   // r=0 element
    uint32_t sbase = 0;
    #pragma unroll
    for (int q = 0; q < NQ; ++q)
        sbase |= (uint32_t)(__popc(masks.m[q] & y0) & 1) << q;

    uint32_t s[16];
    #pragma unroll
    for (int r = 0; r < 16; ++r) s[r] = sbase ^ stab[r];

    // ---- synthesize psi: amp[r] = prod_q v_q[bit] ----
    float2 amp[16];
    #pragma unroll
    for (int r = 0; r < 16; ++r) amp[r] = make_float2(1.f, 0.f);

    #pragma unroll 4
    for (int q = 0; q < NQ; ++q) {
        float2 v0 = v[q][0], v1 = v[q][1];   // wave-uniform LDS broadcast
        #pragma unroll
        for (int r = 0; r < 16; ++r) {
            bool b = (s[r] >> q) & 1u;
            float2 sel = make_float2(b ? v1.x : v0.x, b ? v1.y : v0.y);
            amp[r] = cmul(amp[r], sel);
        }
    }

    // ---- butterfly stages on h-bits 0..5 (lane bits) via shfl_xor ----
    #pragma unroll
    for (int p = 0; p < 6; ++p) {
        const int lm = 1 << p;
        const bool bit = (lane & lm) != 0;
        float2 g00 = U[9 - p][0][0], g01 = U[9 - p][0][1];
        float2 g10 = U[9 - p][1][0], g11 = U[9 - p][1][1];
        // lane bit=0: new = g00*mine + g01*other ; bit=1: new = g11*mine + g10*other
        float2 ga = bit ? g11 : g00;
        float2 gb = bit ? g10 : g01;
        #pragma unroll
        for (int r = 0; r < 16; ++r) {
            float2 mine = amp[r];
            float2 oth = make_float2(__shfl_xor(mine.x, lm, 64),
                                     __shfl_xor(mine.y, lm, 64));
            amp[r] = cadd(cmul(ga, mine), cmul(gb, oth));
        }
    }

    // ---- butterfly stages on h-bits 6..9 (register index bits) ----
    #pragma unroll
    for (int p = 6; p < 10; ++p) {
        const int pb = p - 6;
        float2 g00 = U[9 - p][0][0], g01 = U[9 - p][0][1];
        float2 g10 = U[9 - p][1][0], g11 = U[9 - p][1][1];
        #pragma unroll
        for (int j = 0; j < 8; ++j) {
            int lo = j & ((1 << pb) - 1);
            int r0 = ((j >> pb) << (pb + 1)) | lo;
            int r1 = r0 | (1 << pb);
            float2 a = amp[r0], b = amp[r1];
            amp[r0] = cadd(cmul(g00, a), cmul(g01, b));
            amp[r1] = cadd(cmul(g10, a), cmul(g11, b));
        }
    }

    // ---- |amp|^2 into per-wave LDS slab (stride-1 stores, conflict-free) ----
    #pragma unroll
    for (int r = 0; r < 16; ++r) {
        int h = (r << 6) | lane;
        hid[wave][h] = fmaf(amp[r].x, amp[r].x, amp[r].y * amp[r].y);
    }
    __syncthreads();

    // ---- cross-wave sum + one global atomic per h per block ----
    #pragma unroll
    for (int k = 0; k < NH / BLOCK; ++k) {
        int h = tid + k * BLOCK;
        float acc = hid[0][h] + hid[1][h] + hid[2][h] + hid[3][h];
        atomicAdd(&out[h], acc);
    }
}

extern "C" void kernel_launch(void* const* d_in, const int* in_sizes, int n_in,
                              void* d_out, int out_size, void* d_ws, size_t ws_size,
                              hipStream_t stream) {
    const float* x = (const float*)d_in[0];   // (1, 20) f32
    const float* w = (const float*)d_in[1];   // (60,)   f32
    float* out = (float*)d_out;               // (1, 1024) f32

    // Compose the CNOT block into 20 GF(2) row-masks over the index bits.
    // state_after[y] = state_enc[B y]; reverse-order rule: M[target] ^= M[control].
    MaskArg ma;
    {
        uint32_t M[NQ];
        for (int q = 0; q < NQ; ++q) M[q] = 1u << q;
        for (int q = NQ - 1; q >= 0; --q) {
            M[(q + 2) % NQ] ^= M[q];
            M[(q + 1) % NQ] ^= M[q];
        }
        for (int q = 0; q < NQ; ++q) {        // qubit j -> index bit (19-j)
            uint32_t im = 0;
            for (int j = 0; j < NQ; ++j)
                if ((M[q] >> j) & 1) im |= 1u << (NQ - 1 - j);
            ma.m[q] = im;
        }
    }

    hipMemsetAsync(d_out, 0, (size_t)out_size * sizeof(float), stream);
    qulinear_kernel<<<NBLOCKS, BLOCK, 0, stream>>>(x, w, out, ma);
}

// Round 3
// 66.875 us; speedup vs baseline: 1.2062x; 1.1072x over previous
//
#include <hip/hip_runtime.h>
#include <cstdint>

// QuLinear: 20-qubit circuit -> marginal probs of 10 MSB qubits (1024 floats).
//
// Round-3 design: 4 waves cooperate per l-value, 4 amps/lane (no spill),
// 4 waves/SIMD occupancy.
//   psi(h,l) = prod_q v_q[parity(mask_q & y)], y=(h<<10)|l  (CNOT block is a
//   GF(2)-linear basis permutation, composed on host into 20 row-masks).
//   Final-layer gates on traced-out qubits drop under partial trace; the 10
//   measured-qubit gates U_q are butterfly stages over h. Stage order is free
//   (tensor factors commute):
//     h-bits 0..5 (lane bits)  -> 6 shfl_xor stages   (U[9]..U[4])
//     h-bits 6..7 (reg index)  -> 2 in-register stages (U[3],U[2])
//     h-bits 8..9 (wave index) -> 1 fused 4x4 LDS combine (U[1],U[0])
//   Block = one l; covers each h exactly once -> atomicAdd into 32 l-sliced
//   partial buffers in d_ws, then a tiny reduce kernel sums slices into out.

#define NQ      20
#define NPART   10
#define NH      1024
#define BLOCK   256
#define NSLICE  32

struct MaskArg { uint32_t m[NQ]; };

__device__ __forceinline__ float2 cmul(float2 a, float2 b) {
    return make_float2(fmaf(a.x, b.x, -a.y * b.y), fmaf(a.x, b.y, a.y * b.x));
}
__device__ __forceinline__ float2 cadd(float2 a, float2 b) {
    return make_float2(a.x + b.x, a.y + b.y);
}

__global__ __launch_bounds__(BLOCK, 4) void qulinear_kernel(
        const float* __restrict__ x, const float* __restrict__ w,
        float* __restrict__ ws, MaskArg masks) {
    __shared__ float2 v[NQ][2];          // per-qubit encoding 2-vectors
    __shared__ float2 U[NPART][2][2];    // Rx*Rz*Rx for measured qubits
    __shared__ float2 ex[4][4][64];      // cross-wave exchange (8 KB)

    const int tid = threadIdx.x;

    // ---- block setup ----
    if (tid < NQ) {
        float xq = x[tid];
        float th = atanf(xq);
        float ph = atanf(xq * xq);
        float c, s, cp, sp;
        __sincosf(0.5f * th, &s, &c);
        __sincosf(0.5f * ph, &sp, &cp);
        float a = (c - s) * 0.70710678118654752f;
        float b = (c + s) * 0.70710678118654752f;
        v[tid][0] = make_float2(a * cp, -a * sp);
        v[tid][1] = make_float2(b * cp,  b * sp);
    }
    if (tid < NPART) {
        const float WM = 0.63245553203367590f;   // sqrt(2/5)
        float a0 = w[3 * tid + 0] * WM;
        float a1 = w[3 * tid + 1] * WM;
        float a2 = w[3 * tid + 2] * WM;
        float c0, s0, c1, s1, c2, s2;
        __sincosf(0.5f * a0, &s0, &c0);
        __sincosf(0.5f * a1, &s1, &c1);
        __sincosf(0.5f * a2, &s2, &c2);
        float2 e0 = make_float2(c1, -s1), e1 = make_float2(c1, s1);
        float2 m00 = cmul(e0, make_float2(c0, 0.f));
        float2 m01 = cmul(e0, make_float2(0.f, -s0));
        float2 m10 = cmul(e1, make_float2(0.f, -s0));
        float2 m11 = cmul(e1, make_float2(c0, 0.f));
        float2 r00 = make_float2(c2, 0.f), r01 = make_float2(0.f, -s2);
        U[tid][0][0] = cadd(cmul(r00, m00), cmul(r01, m10));
        U[tid][0][1] = cadd(cmul(r00, m01), cmul(r01, m11));
        U[tid][1][0] = cadd(cmul(r01, m00), cmul(r00, m10));
        U[tid][1][1] = cadd(cmul(r01, m01), cmul(r00, m11));
    }
    __syncthreads();

    const int wq   = tid >> 6;           // wave index = h-bits 8..9
    const int lane = tid & 63;           // h-bits 0..5
    const uint32_t l = blockIdx.x;

    // ---- per-lane packed parity words ----
    // y-bit map: l -> 0..9, lane -> 10..15, r -> 16..17, wq -> 18..19
    const uint32_t y0 = ((uint32_t)lane << NPART) | l | ((uint32_t)wq << 18);
    uint32_t sbase = 0, d16 = 0, d17 = 0;
    #pragma unroll
    for (int q = 0; q < NQ; ++q) {
        sbase |= (uint32_t)(__popc(masks.m[q] & y0) & 1) << q;
        d16   |= (uint32_t)((masks.m[q] >> 16) & 1u) << q;
        d17   |= (uint32_t)((masks.m[q] >> 17) & 1u) << q;
    }
    uint32_t s[4];
    s[0] = sbase; s[1] = sbase ^ d16; s[2] = sbase ^ d17; s[3] = sbase ^ d16 ^ d17;

    // ---- wave-uniform row of the 4x4 cross-wave matrix G = U0 (x) U1 ----
    float2 g[4];
    #pragma unroll
    for (int j = 0; j < 4; ++j)
        g[j] = cmul(U[0][wq >> 1][j >> 1], U[1][wq & 1][j & 1]);

    // ---- synthesize psi: amp[r] = prod_q v_q[bit] ----
    float2 amp[4];
    #pragma unroll
    for (int r = 0; r < 4; ++r) amp[r] = make_float2(1.f, 0.f);

    #pragma unroll
    for (int q = 0; q < NQ; ++q) {
        float2 v0 = v[q][0], v1 = v[q][1];   // wave-uniform LDS broadcast
        #pragma unroll
        for (int r = 0; r < 4; ++r) {
            bool b = (s[r] >> q) & 1u;
            float2 sel = make_float2(b ? v1.x : v0.x, b ? v1.y : v0.y);
            amp[r] = cmul(amp[r], sel);
        }
    }

    // ---- in-register stages: h-bit 6 (U[3]), h-bit 7 (U[2]) ----
    {
        float2 g00 = U[3][0][0], g01 = U[3][0][1], g10 = U[3][1][0], g11 = U[3][1][1];
        float2 a, b;
        a = amp[0]; b = amp[1];
        amp[0] = cadd(cmul(g00, a), cmul(g01, b));
        amp[1] = cadd(cmul(g10, a), cmul(g11, b));
        a = amp[2]; b = amp[3];
        amp[2] = cadd(cmul(g00, a), cmul(g01, b));
        amp[3] = cadd(cmul(g10, a), cmul(g11, b));
    }
    {
        float2 g00 = U[2][0][0], g01 = U[2][0][1], g10 = U[2][1][0], g11 = U[2][1][1];
        float2 a, b;
        a = amp[0]; b = amp[2];
        amp[0] = cadd(cmul(g00, a), cmul(g01, b));
        amp[2] = cadd(cmul(g10, a), cmul(g11, b));
        a = amp[1]; b = amp[3];
        amp[1] = cadd(cmul(g00, a), cmul(g01, b));
        amp[3] = cadd(cmul(g10, a), cmul(g11, b));
    }

    // ---- shfl stages: h-bits 0..5 (U[9]..U[4]) ----
    #pragma unroll
    for (int p = 0; p < 6; ++p) {
        const int lm = 1 << p;
        const bool bit = (lane & lm) != 0;
        float2 g00 = U[9 - p][0][0], g01 = U[9 - p][0][1];
        float2 g10 = U[9 - p][1][0], g11 = U[9 - p][1][1];
        float2 ga = bit ? g11 : g00;
        float2 gb = bit ? g10 : g01;
        #pragma unroll
        for (int r = 0; r < 4; ++r) {
            float2 mine = amp[r];
            float2 oth = make_float2(__shfl_xor(mine.x, lm, 64),
                                     __shfl_xor(mine.y, lm, 64));
            amp[r] = cadd(cmul(ga, mine), cmul(gb, oth));
        }
    }

    // ---- cross-wave stage: h-bits 8..9 via fused 4x4 LDS combine ----
    #pragma unroll
    for (int r = 0; r < 4; ++r) ex[wq][r][lane] = amp[r];
    __syncthreads();
    #pragma unroll
    for (int r = 0; r < 4; ++r) {
        float2 acc = cmul(g[0], ex[0][r][lane]);
        acc = cadd(acc, cmul(g[1], ex[1][r][lane]));
        acc = cadd(acc, cmul(g[2], ex[2][r][lane]));
        acc = cadd(acc, cmul(g[3], ex[3][r][lane]));
        amp[r] = acc;
    }

    // ---- |amp|^2 -> sliced partial buffers (each h once per block) ----
    float* wsp = ws + (size_t)(blockIdx.x & (NSLICE - 1)) * NH;
    #pragma unroll
    for (int r = 0; r < 4; ++r) {
        int h = (wq << 8) | (r << 6) | lane;
        atomicAdd(&wsp[h], fmaf(amp[r].x, amp[r].x, amp[r].y * amp[r].y));
    }
}

__global__ __launch_bounds__(BLOCK) void reduce_kernel(
        const float* __restrict__ ws, float* __restrict__ out) {
    int h = blockIdx.x * BLOCK + threadIdx.x;
    float acc = 0.f;
    #pragma unroll
    for (int s = 0; s < NSLICE; ++s) acc += ws[s * NH + h];
    out[h] = acc;
}

extern "C" void kernel_launch(void* const* d_in, const int* in_sizes, int n_in,
                              void* d_out, int out_size, void* d_ws, size_t ws_size,
                              hipStream_t stream) {
    const float* x = (const float*)d_in[0];   // (1, 20) f32
    const float* w = (const float*)d_in[1];   // (60,)   f32
    float* out = (float*)d_out;               // (1, 1024) f32

    // Compose the CNOT block into 20 GF(2) row-masks over the index bits.
    // state_after[y] = state_enc[B y]; reverse-order rule: M[target] ^= M[control].
    MaskArg ma;
    {
        uint32_t M[NQ];
        for (int q = 0; q < NQ; ++q) M[q] = 1u << q;
        for (int q = NQ - 1; q >= 0; --q) {
            M[(q + 2) % NQ] ^= M[q];
            M[(q + 1) % NQ] ^= M[q];
        }
        for (int q = 0; q < NQ; ++q) {        // qubit j -> index bit (19-j)
            uint32_t im = 0;
            for (int j = 0; j < NQ; ++j)
                if ((M[q] >> j) & 1) im |= 1u << (NQ - 1 - j);
            ma.m[q] = im;
        }
    }

    hipMemsetAsync(d_ws, 0, (size_t)NSLICE * NH * sizeof(float), stream);
    qulinear_kernel<<<NH, BLOCK, 0, stream>>>(x, w, (float*)d_ws, ma);
    reduce_kernel<<<NH / BLOCK, BLOCK, 0, stream>>>((const float*)d_ws, out);
}